// Round 5
// baseline (1100.000 us; speedup 1.0000x reference)
//
#include <hip/hip_runtime.h>
#include <math.h>

// ---------------------------------------------------------------------------
// SNAT3: 4-layer GAT-like GNN. N=50000, E=800000, HID=64, fp32.
// R5 dense-kernel structure: lane = node (64-thread blocks, 1 wave each).
//   - acc[64] output features per lane in VGPRs (fully unrolled)
//   - activations: per-lane register tiles from the lane's own global row
//   - weights: wave-uniform scalar loads (s_load) from TRANSPOSED Wt[f][k]
//     copies built once per launch by k_prep -> v_fma_f32 v,v,s,v
//   - zero LDS in inner loops (R4 was LDS-pipe bound: 119 LDS cyc / 64 VALU
//     cyc per k4; LDS pipe is per-CU shared by 4 SIMDs)
// k_mlp fuses all 3 MLP layers; layer-1 activations never leave registers.
// ---------------------------------------------------------------------------

// Wt workspace layout (floats):
//   [0,8192)        Wt_embed [64][128]
//   [8192,24576)    Wt_gat l=0..3, each [64][64]
//   [24576,40960)   Wt0 [64][256]
//   [40960,45056)   Wt1 [64][64]
#define WT_EMB 0
#define WT_GAT 8192
#define WT_W0  24576
#define WT_W1  40960
#define WT_TOT 45056

__global__ void k_prep(const float* __restrict__ We, const float* __restrict__ Wg,
                       const float* __restrict__ W0, const float* __restrict__ W1,
                       float* __restrict__ wt, int* __restrict__ counts, int N) {
  int i = blockIdx.x * 256 + threadIdx.x;
  if (i < N) counts[i] = 0;
  if (i < 8192) {                       // W_embed [128][64] -> Wt[f][k]
    int k = i >> 6, f = i & 63;
    wt[WT_EMB + f * 128 + k] = We[i];
  } else if (i < 24576) {               // W_gat [4][64][64]
    int j = i - 8192, l = j >> 12, r = j & 4095;
    int k = r >> 6, f = r & 63;
    wt[WT_GAT + l * 4096 + f * 64 + k] = Wg[j];
  } else if (i < 40960) {               // W0 [256][64]
    int j = i - 24576, k = j >> 6, f = j & 63;
    wt[WT_W0 + f * 256 + k] = W0[j];
  } else if (i < WT_TOT) {              // W1 [64][64]
    int j = i - 40960, k = j >> 6, f = j & 63;
    wt[WT_W1 + f * 64 + k] = W1[j];
  }
}

__global__ void k_hist(const int* __restrict__ dst, int* __restrict__ counts, int E) {
  int e = blockIdx.x * blockDim.x + threadIdx.x;
  if (e < E) atomicAdd(&counts[dst[e]], 1);
}

__global__ __launch_bounds__(1024) void k_bsum(const int* __restrict__ counts,
                                               int* __restrict__ bsum, int n) {
  __shared__ int wsum[16];
  int tid = threadIdx.x, lane = tid & 63, wid = tid >> 6;
  int i = blockIdx.x * 1024 + tid;
  int v = (i < n) ? counts[i] : 0;
  #pragma unroll
  for (int off = 32; off; off >>= 1) v += __shfl_xor(v, off, 64);
  if (lane == 0) wsum[wid] = v;
  __syncthreads();
  if (wid == 0) {
    int w = (lane < 16) ? wsum[lane] : 0;
    #pragma unroll
    for (int off = 8; off; off >>= 1) w += __shfl_xor(w, off, 64);
    if (lane == 0) bsum[blockIdx.x] = w;
  }
}

__global__ __launch_bounds__(64) void k_bscan(const int* __restrict__ bsum,
                                              int* __restrict__ bofs,
                                              int* __restrict__ row_ptr,
                                              int nb, int n) {
  int lane = threadIdx.x;
  int carry = 0;
  for (int base = 0; base < nb; base += 64) {
    int idx = base + lane;
    int orig = (idx < nb) ? bsum[idx] : 0;
    int inc = orig;
    #pragma unroll
    for (int off = 1; off < 64; off <<= 1) {
      int t = __shfl_up(inc, off, 64);
      if (lane >= off) inc += t;
    }
    if (idx < nb) bofs[idx] = carry + inc - orig;
    carry += __shfl(inc, 63, 64);
  }
  if (lane == 0) row_ptr[n] = carry;
}

__global__ __launch_bounds__(1024) void k_scan3(const int* __restrict__ counts,
                                                const int* __restrict__ bofs,
                                                int* __restrict__ row_ptr,
                                                int* __restrict__ cursor, int n) {
  __shared__ int wsum[16];
  int tid = threadIdx.x, lane = tid & 63, wid = tid >> 6;
  int i = blockIdx.x * 1024 + tid;
  int v = (i < n) ? counts[i] : 0;
  int inc = v;
  #pragma unroll
  for (int off = 1; off < 64; off <<= 1) {
    int t = __shfl_up(inc, off, 64);
    if (lane >= off) inc += t;
  }
  if (lane == 63) wsum[wid] = inc;
  __syncthreads();
  if (wid == 0 && lane < 16) {
    int orig = wsum[lane];
    int w = orig;
    #pragma unroll
    for (int off = 1; off < 16; off <<= 1) {
      int t = __shfl_up(w, off, 64);
      if (lane >= off) w += t;
    }
    wsum[lane] = w - orig;
  }
  __syncthreads();
  int excl = bofs[blockIdx.x] + wsum[wid] + inc - v;
  if (i < n) { row_ptr[i] = excl; cursor[i] = excl; }
}

__global__ void k_scatter(const int* __restrict__ src, const int* __restrict__ dst,
                          int* __restrict__ cursor, int* __restrict__ csr_src, int E) {
  int e = blockIdx.x * blockDim.x + threadIdx.x;
  if (e < E) {
    int pos = atomicAdd(&cursor[dst[e]], 1);
    csr_src[pos] = src[e];
  }
}

// ---- h = tanh(x @ W_embed)   lane=node; weights via s_load from Wt ----
__global__ __launch_bounds__(64) void k_embed(const float* __restrict__ x,
                                              const float* __restrict__ wt,
                                              float* __restrict__ h, int N) {
  int lane = threadIdx.x;
  int n = blockIdx.x * 64 + lane;
  int nn = min(n, N - 1);
  const float* xp = x + (size_t)nn * 128;
  float acc[64];
  #pragma unroll
  for (int f = 0; f < 64; f++) acc[f] = 0.f;
  for (int kt = 0; kt < 8; kt++) {
    float4 v0 = *(const float4*)(xp + kt * 16 + 0);
    float4 v1 = *(const float4*)(xp + kt * 16 + 4);
    float4 v2 = *(const float4*)(xp + kt * 16 + 8);
    float4 v3 = *(const float4*)(xp + kt * 16 + 12);
    float a[16] = {v0.x, v0.y, v0.z, v0.w, v1.x, v1.y, v1.z, v1.w,
                   v2.x, v2.y, v2.z, v2.w, v3.x, v3.y, v3.z, v3.w};
    const float* wb = wt + kt * 16;
    #pragma unroll
    for (int f = 0; f < 64; f++) {
      const float* wr = wb + f * 128;   // uniform address -> s_load
      #pragma unroll
      for (int k = 0; k < 16; k++) acc[f] = fmaf(a[k], wr[k], acc[f]);
    }
  }
  if (n < N) {
    float* hp = h + (size_t)n * 64;
    #pragma unroll
    for (int f = 0; f < 64; f++) hp[f] = tanhf(acc[f]);
  }
}

// ---- feat = hin @ Wg; el/er per-lane dot products ----
__global__ __launch_bounds__(64) void k_feat(const float* __restrict__ hin,
                                             const float* __restrict__ wt,
                                             const float* __restrict__ al,
                                             const float* __restrict__ ar,
                                             float* __restrict__ feat,
                                             float* __restrict__ el,
                                             float* __restrict__ er, int N) {
  int lane = threadIdx.x;
  int n = blockIdx.x * 64 + lane;
  int nn = min(n, N - 1);
  const float* hp = hin + (size_t)nn * 64;
  float acc[64];
  #pragma unroll
  for (int f = 0; f < 64; f++) acc[f] = 0.f;
  for (int kt = 0; kt < 4; kt++) {
    float4 v0 = *(const float4*)(hp + kt * 16 + 0);
    float4 v1 = *(const float4*)(hp + kt * 16 + 4);
    float4 v2 = *(const float4*)(hp + kt * 16 + 8);
    float4 v3 = *(const float4*)(hp + kt * 16 + 12);
    float a[16] = {v0.x, v0.y, v0.z, v0.w, v1.x, v1.y, v1.z, v1.w,
                   v2.x, v2.y, v2.z, v2.w, v3.x, v3.y, v3.z, v3.w};
    const float* wb = wt + kt * 16;
    #pragma unroll
    for (int f = 0; f < 64; f++) {
      const float* wr = wb + f * 64;    // uniform -> s_load
      #pragma unroll
      for (int k = 0; k < 16; k++) acc[f] = fmaf(a[k], wr[k], acc[f]);
    }
  }
  float rl = 0.f, rr = 0.f;
  #pragma unroll
  for (int f = 0; f < 64; f++) {
    rl = fmaf(acc[f], al[f], rl);       // al/ar uniform scalar loads
    rr = fmaf(acc[f], ar[f], rr);
  }
  if (n < N) {
    float* fp = feat + (size_t)n * 64;
    #pragma unroll
    for (int f4 = 0; f4 < 16; f4++)
      *(float4*)(fp + f4 * 4) = make_float4(acc[f4 * 4 + 0], acc[f4 * 4 + 1],
                                            acc[f4 * 4 + 2], acc[f4 * 4 + 3]);
    el[n] = rl;
    er[n] = rr;
  }
}

// ---- edge softmax + aggregate: one wave per dst node, lane = feature ----
__global__ __launch_bounds__(256) void k_aggr(const float* __restrict__ feat,
                                              const float* __restrict__ el,
                                              const float* __restrict__ er,
                                              const int* __restrict__ row_ptr,
                                              const int* __restrict__ csr_src,
                                              unsigned char* __restrict__ mask,
                                              int write_mask, int use_mask,
                                              float* __restrict__ hout, int N) {
  __shared__ __align__(16) int   su[4][64];
  __shared__ __align__(16) float spl[4][64];
  int wv = (int)((blockIdx.x * blockDim.x + threadIdx.x) >> 6);
  int wave = threadIdx.x >> 6, lane = threadIdx.x & 63;
  if (wv >= N) return;
  int beg = row_ptr[wv], end = row_ptr[wv + 1];
  int deg = end - beg;
  float erv = er[wv];
  float acc0 = 0.f, acc1 = 0.f, acc2 = 0.f, acc3 = 0.f;
  if (deg <= 64) {
    int k = beg + lane;
    bool have = (lane < deg);
    int u = have ? csr_src[k] : 0;
    float sc = -INFINITY;
    if (have) {
      float e0 = el[u] + erv;
      sc = (e0 >= 0.f) ? e0 : 0.2f * e0;              // leaky_relu(0.2)
      if (use_mask && mask[k] == 0) sc = -1e9f;       // pruned
    }
    float m = sc;
    #pragma unroll
    for (int off = 32; off; off >>= 1) m = fmaxf(m, __shfl_xor(m, off, 64));
    float pl = have ? expf(sc - m) : 0.f;
    float s = pl;
    #pragma unroll
    for (int off = 32; off; off >>= 1) s += __shfl_xor(s, off, 64);
    pl *= 1.0f / fmaxf(s, 1e-9f);                     // alpha
    if (write_mask && have) mask[k] = (pl >= 0.01f) ? 1 : 0;
    su[wave][lane] = u;
    spl[wave][lane] = pl;                             // 0 for tail lanes
    int dq = (deg + 3) >> 2;
    #pragma unroll 2
    for (int q = 0; q < dq; q++) {
      int4   uu = *(const int4*)&su[wave][q * 4];
      float4 pp = *(const float4*)&spl[wave][q * 4];
      acc0 = fmaf(pp.x, feat[(size_t)uu.x * 64 + lane], acc0);
      acc1 = fmaf(pp.y, feat[(size_t)uu.y * 64 + lane], acc1);
      acc2 = fmaf(pp.z, feat[(size_t)uu.z * 64 + lane], acc2);
      acc3 = fmaf(pp.w, feat[(size_t)uu.w * 64 + lane], acc3);
    }
  } else {
    float m = -INFINITY, s = 0.f;
    for (int base = beg; base < end; base += 64) {
      int k = base + lane;
      float sc = -INFINITY;
      if (k < end) {
        int u = csr_src[k];
        float e0 = el[u] + erv;
        sc = (e0 >= 0.f) ? e0 : 0.2f * e0;
        if (use_mask && mask[k] == 0) sc = -1e9f;
      }
      float cm = sc;
      #pragma unroll
      for (int off = 32; off; off >>= 1) cm = fmaxf(cm, __shfl_xor(cm, off, 64));
      float nm = fmaxf(m, cm);
      float t = (k < end) ? expf(sc - nm) : 0.f;
      #pragma unroll
      for (int off = 32; off; off >>= 1) t += __shfl_xor(t, off, 64);
      s = s * expf(m - nm) + t;
      m = nm;
    }
    float inv = 1.0f / fmaxf(s, 1e-9f);
    for (int base = beg; base < end; base += 64) {
      int k = base + lane;
      int u = 0;
      float pl = 0.f;
      if (k < end) {
        u = csr_src[k];
        float e0 = el[u] + erv;
        float sc = (e0 >= 0.f) ? e0 : 0.2f * e0;
        if (use_mask && mask[k] == 0) sc = -1e9f;
        pl = expf(sc - m) * inv;
        if (write_mask) mask[k] = (pl >= 0.01f) ? 1 : 0;
      }
      su[wave][lane] = u;
      spl[wave][lane] = pl;
      int cnt = min(64, end - base);
      int dq = (cnt + 3) >> 2;
      for (int q = 0; q < dq; q++) {
        int4   uu = *(const int4*)&su[wave][q * 4];
        float4 pp = *(const float4*)&spl[wave][q * 4];
        acc0 = fmaf(pp.x, feat[(size_t)uu.x * 64 + lane], acc0);
        acc1 = fmaf(pp.y, feat[(size_t)uu.y * 64 + lane], acc1);
        acc2 = fmaf(pp.z, feat[(size_t)uu.z * 64 + lane], acc2);
        acc3 = fmaf(pp.w, feat[(size_t)uu.w * 64 + lane], acc3);
      }
    }
  }
  float acc = (acc0 + acc1) + (acc2 + acc3);
  hout[(size_t)wv * 64 + lane] = (acc > 0.f) ? acc : expm1f(acc);  // elu
}

// ---- fused MLP head: lane=node; layer-1 acts stay in registers ----
__global__ __launch_bounds__(64) void k_mlp(const float* __restrict__ o0,
                                            const float* __restrict__ o1,
                                            const float* __restrict__ o2,
                                            const float* __restrict__ o3,
                                            const float* __restrict__ wt0,
                                            const float* __restrict__ b0,
                                            const float* __restrict__ wt1,
                                            const float* __restrict__ b1,
                                            const float* __restrict__ W2,
                                            const float* __restrict__ b2,
                                            float* __restrict__ out, int N) {
  int lane = threadIdx.x;
  int n = blockIdx.x * 64 + lane;
  int nn = min(n, N - 1);
  const float* segs[4] = {o0 + (size_t)nn * 64, o1 + (size_t)nn * 64,
                          o2 + (size_t)nn * 64, o3 + (size_t)nn * 64};
  float acc[64];
  #pragma unroll
  for (int f = 0; f < 64; f++) acc[f] = b0[f];        // uniform loads
  for (int kt = 0; kt < 16; kt++) {
    const float* sp = segs[kt >> 2] + (kt & 3) * 16;
    float4 v0 = *(const float4*)(sp + 0);
    float4 v1 = *(const float4*)(sp + 4);
    float4 v2 = *(const float4*)(sp + 8);
    float4 v3 = *(const float4*)(sp + 12);
    float a[16] = {v0.x, v0.y, v0.z, v0.w, v1.x, v1.y, v1.z, v1.w,
                   v2.x, v2.y, v2.z, v2.w, v3.x, v3.y, v3.z, v3.w};
    const float* wb = wt0 + kt * 16;
    #pragma unroll
    for (int f = 0; f < 64; f++) {
      const float* wr = wb + f * 256;   // uniform -> s_load
      #pragma unroll
      for (int k = 0; k < 16; k++) acc[f] = fmaf(a[k], wr[k], acc[f]);
    }
  }
  #pragma unroll
  for (int f = 0; f < 64; f++) acc[f] = (acc[f] > 0.f) ? acc[f] : 0.f;  // relu
  // layers 1+2 fused: 16-feature chunks of a1; acts (acc) in registers
  float r = 0.f;
  for (int fc = 0; fc < 4; fc++) {
    float a1[16];
    #pragma unroll
    for (int j = 0; j < 16; j++) a1[j] = b1[fc * 16 + j];
    #pragma unroll
    for (int j = 0; j < 16; j++) {
      const float* wr = wt1 + (fc * 16 + j) * 64;     // uniform -> s_load
      #pragma unroll
      for (int k = 0; k < 64; k++) a1[j] = fmaf(acc[k], wr[k], a1[j]);
    }
    #pragma unroll
    for (int j = 0; j < 16; j++) {
      float t = (a1[j] > 0.f) ? a1[j] : 0.f;          // relu
      r = fmaf(t, W2[fc * 16 + j], r);                // uniform
    }
  }
  if (n < N) {
    float o = r + b2[0];
    out[n] = (o > 0.f) ? o : 0.f;                     // final relu
  }
}

extern "C" void kernel_launch(void* const* d_in, const int* in_sizes, int n_in,
                              void* d_out, int out_size, void* d_ws, size_t ws_size,
                              hipStream_t stream) {
  const float* x       = (const float*)d_in[0];
  const int*   esrc    = (const int*)d_in[1];
  const int*   edst    = (const int*)d_in[2];
  const float* W_embed = (const float*)d_in[3];
  const float* W_gat   = (const float*)d_in[4];
  const float* a_l     = (const float*)d_in[5];
  const float* a_r     = (const float*)d_in[6];
  const float* W0      = (const float*)d_in[7];
  const float* b0      = (const float*)d_in[8];
  const float* W1      = (const float*)d_in[9];
  const float* b1      = (const float*)d_in[10];
  const float* W2      = (const float*)d_in[11];
  const float* b2      = (const float*)d_in[12];
  float* out = (float*)d_out;
  const int N = in_sizes[0] / 128;
  const int E = in_sizes[1];

  char* p = (char*)d_ws;
  auto alloc = [&](size_t bytes) -> char* {
    char* r = p;
    p += (bytes + 255) & ~(size_t)255;
    return r;
  };
  float* out0 = (float*)alloc((size_t)N * 64 * 4);
  float* out1 = (float*)alloc((size_t)N * 64 * 4);
  float* out2 = (float*)alloc((size_t)N * 64 * 4);
  float* out3 = (float*)alloc((size_t)N * 64 * 4);
  float* h    = out3;  // alias: h dead before out3 written
  float* feat = (float*)alloc((size_t)N * 64 * 4);
  float* el   = (float*)alloc((size_t)N * 4);
  float* er   = (float*)alloc((size_t)N * 4);
  int* counts  = (int*)alloc((size_t)N * 4);
  int* row_ptr = (int*)alloc((size_t)(N + 1) * 4);
  int* cursor  = (int*)alloc((size_t)N * 4);
  int* csr_src = (int*)alloc((size_t)E * 4);
  unsigned char* mask = (unsigned char*)alloc((size_t)E);
  int nb = (N + 1023) / 1024;
  int* bsum = (int*)alloc((size_t)nb * 4);
  int* bofs = (int*)alloc((size_t)nb * 4);
  float* wt = (float*)alloc((size_t)WT_TOT * 4);

  // --- prep: zero counts + transpose all weight matrices ---
  int prep_n = (N > WT_TOT) ? N : WT_TOT;
  k_prep<<<(prep_n + 255) / 256, 256, 0, stream>>>(W_embed, W_gat, W0, W1,
                                                   wt, counts, N);

  // --- CSR build (dst-sorted) ---
  k_hist<<<(E + 255) / 256, 256, 0, stream>>>(edst, counts, E);
  k_bsum<<<nb, 1024, 0, stream>>>(counts, bsum, N);
  k_bscan<<<1, 64, 0, stream>>>(bsum, bofs, row_ptr, nb, N);
  k_scan3<<<nb, 1024, 0, stream>>>(counts, bofs, row_ptr, cursor, N);
  k_scatter<<<(E + 255) / 256, 256, 0, stream>>>(esrc, edst, cursor, csr_src, E);

  // --- embed ---
  int nwb = (N + 63) / 64;   // 64-thread blocks, lane = node
  k_embed<<<nwb, 64, 0, stream>>>(x, wt + WT_EMB, h, N);

  // --- 4 conv layers ---
  const float* hin = h;
  float* outs[4] = {out0, out1, out2, out3};
  for (int l = 0; l < 4; l++) {
    k_feat<<<nwb, 64, 0, stream>>>(hin, wt + WT_GAT + (size_t)l * 4096,
                                   a_l + (size_t)l * 64, a_r + (size_t)l * 64,
                                   feat, el, er, N);
    k_aggr<<<(N + 3) / 4, 256, 0, stream>>>(feat, el, er, row_ptr, csr_src, mask,
                                            (l == 0) ? 1 : 0, (l > 0) ? 1 : 0,
                                            outs[l], N);
    hin = outs[l];
  }

  // --- MLP head ---
  k_mlp<<<nwb, 64, 0, stream>>>(out0, out1, out2, out3, wt + WT_W0, b0,
                                wt + WT_W1, b1, W2, b2, out, N);
}

// Round 6
// 526.850 us; speedup vs baseline: 2.0879x; 2.0879x over previous
//
#include <hip/hip_runtime.h>
#include <math.h>

// ---------------------------------------------------------------------------
// SNAT3: 4-layer GAT GNN. N=50000, E=800000, HID=64, fp32.
// R6 dense structure: block=256thr=64 nodes, lane=node; wave w owns features
// [16w,16w+16). Acts staged to LDS once per block (coalesced), hoisted to 64
// per-lane VGPRs; weights are wave-uniform scalar loads (s_load) from
// transposed wt[f][k] (readfirstlane on the f-chunk base). Inner loops are
// pure v_fma v,v,s,v  — zero LDS/VMEM per FMA (R4 was LDS-pipe bound; R5 had
// the right inner loop but only 782 waves -> latency-starved).
// ---------------------------------------------------------------------------

#define WT_EMB 0
#define WT_GAT 8192
#define WT_W0  24576
#define WT_W1  40960
#define WT_TOT 45056

__global__ void k_prep(const float* __restrict__ We, const float* __restrict__ Wg,
                       const float* __restrict__ W0, const float* __restrict__ W1,
                       float* __restrict__ wt, int* __restrict__ counts, int N) {
  int i = blockIdx.x * 256 + threadIdx.x;
  if (i < N) counts[i] = 0;
  if (i < 8192) {                       // W_embed [128][64] -> [64f][128k]
    int k = i >> 6, f = i & 63;
    wt[WT_EMB + f * 128 + k] = We[i];
  } else if (i < 24576) {               // W_gat [4][64][64] -> [4][64f][64k]
    int j = i - 8192, l = j >> 12, r = j & 4095;
    int k = r >> 6, f = r & 63;
    wt[WT_GAT + l * 4096 + f * 64 + k] = Wg[j];
  } else if (i < 40960) {               // W0 [256][64] -> [64f][256k]
    int j = i - 24576, k = j >> 6, f = j & 63;
    wt[WT_W0 + f * 256 + k] = W0[j];
  } else if (i < WT_TOT) {              // W1 [64][64] -> [64f][64k]
    int j = i - 40960, k = j >> 6, f = j & 63;
    wt[WT_W1 + f * 64 + k] = W1[j];
  }
}

__global__ void k_hist(const int* __restrict__ dst, int* __restrict__ counts, int E) {
  int e = blockIdx.x * blockDim.x + threadIdx.x;
  if (e < E) atomicAdd(&counts[dst[e]], 1);
}

__global__ __launch_bounds__(1024) void k_bsum(const int* __restrict__ counts,
                                               int* __restrict__ bsum, int n) {
  __shared__ int wsum[16];
  int tid = threadIdx.x, lane = tid & 63, wid = tid >> 6;
  int i = blockIdx.x * 1024 + tid;
  int v = (i < n) ? counts[i] : 0;
  #pragma unroll
  for (int off = 32; off; off >>= 1) v += __shfl_xor(v, off, 64);
  if (lane == 0) wsum[wid] = v;
  __syncthreads();
  if (wid == 0) {
    int w = (lane < 16) ? wsum[lane] : 0;
    #pragma unroll
    for (int off = 8; off; off >>= 1) w += __shfl_xor(w, off, 64);
    if (lane == 0) bsum[blockIdx.x] = w;
  }
}

__global__ __launch_bounds__(64) void k_bscan(const int* __restrict__ bsum,
                                              int* __restrict__ bofs,
                                              int* __restrict__ row_ptr,
                                              int nb, int n) {
  int lane = threadIdx.x;
  int carry = 0;
  for (int base = 0; base < nb; base += 64) {
    int idx = base + lane;
    int orig = (idx < nb) ? bsum[idx] : 0;
    int inc = orig;
    #pragma unroll
    for (int off = 1; off < 64; off <<= 1) {
      int t = __shfl_up(inc, off, 64);
      if (lane >= off) inc += t;
    }
    if (idx < nb) bofs[idx] = carry + inc - orig;
    carry += __shfl(inc, 63, 64);
  }
  if (lane == 0) row_ptr[n] = carry;
}

__global__ __launch_bounds__(1024) void k_scan3(const int* __restrict__ counts,
                                                const int* __restrict__ bofs,
                                                int* __restrict__ row_ptr,
                                                int* __restrict__ cursor, int n) {
  __shared__ int wsum[16];
  int tid = threadIdx.x, lane = tid & 63, wid = tid >> 6;
  int i = blockIdx.x * 1024 + tid;
  int v = (i < n) ? counts[i] : 0;
  int inc = v;
  #pragma unroll
  for (int off = 1; off < 64; off <<= 1) {
    int t = __shfl_up(inc, off, 64);
    if (lane >= off) inc += t;
  }
  if (lane == 63) wsum[wid] = inc;
  __syncthreads();
  if (wid == 0 && lane < 16) {
    int orig = wsum[lane];
    int w = orig;
    #pragma unroll
    for (int off = 1; off < 16; off <<= 1) {
      int t = __shfl_up(w, off, 64);
      if (lane >= off) w += t;
    }
    wsum[lane] = w - orig;
  }
  __syncthreads();
  int excl = bofs[blockIdx.x] + wsum[wid] + inc - v;
  if (i < n) { row_ptr[i] = excl; cursor[i] = excl; }
}

__global__ void k_scatter(const int* __restrict__ src, const int* __restrict__ dst,
                          int* __restrict__ cursor, int* __restrict__ csr_src, int E) {
  int e = blockIdx.x * blockDim.x + threadIdx.x;
  if (e < E) {
    int pos = atomicAdd(&cursor[dst[e]], 1);
    csr_src[pos] = src[e];
  }
}

// ---- h = tanh(x @ W_embed); block=64 nodes, wave=16-feature chunk ----
__global__ __launch_bounds__(256) void k_embed(const float* __restrict__ x,
                                               const float* __restrict__ wt,
                                               float* __restrict__ h, int N) {
  __shared__ float sA[64 * 129];   // acts [node][k0..127], pad129 -> 2-way banks
  int tid = threadIdx.x, lane = tid & 63, wv = tid >> 6;
  int nb0 = blockIdx.x * 64;
  int nl = N - 1;
  {  // cooperative stage: thread t -> row r=t>>2, quarter p=t&3, both halves
    int r = tid >> 2, p = tid & 3;
    const float* gp = x + (size_t)min(nb0 + r, nl) * 128;
    #pragma unroll
    for (int half = 0; half < 2; half++) {
      const float* g = gp + half * 64 + p * 16;
      float4 v0 = *(const float4*)(g + 0), v1 = *(const float4*)(g + 4);
      float4 v2 = *(const float4*)(g + 8), v3 = *(const float4*)(g + 12);
      float* dp = &sA[r * 129 + half * 64 + p * 16];
      dp[0]=v0.x; dp[1]=v0.y; dp[2]=v0.z; dp[3]=v0.w;
      dp[4]=v1.x; dp[5]=v1.y; dp[6]=v1.z; dp[7]=v1.w;
      dp[8]=v2.x; dp[9]=v2.y; dp[10]=v2.z; dp[11]=v2.w;
      dp[12]=v3.x; dp[13]=v3.y; dp[14]=v3.z; dp[15]=v3.w;
    }
  }
  __syncthreads();
  int f0 = __builtin_amdgcn_readfirstlane(wv * 16);
  float acc[16];
  #pragma unroll
  for (int f = 0; f < 16; f++) acc[f] = 0.f;
  for (int kc = 0; kc < 2; kc++) {
    float a[64];
    #pragma unroll
    for (int k = 0; k < 64; k++) a[k] = sA[lane * 129 + kc * 64 + k];
    #pragma unroll
    for (int f = 0; f < 16; f++) {
      const float* wr = wt + (f0 + f) * 128 + kc * 64;   // uniform -> s_load
      #pragma unroll
      for (int k = 0; k < 64; k++) acc[f] = fmaf(a[k], wr[k], acc[f]);
    }
  }
  __syncthreads();   // all act reads done; reuse sA (as 64x65) for h transpose
  #pragma unroll
  for (int f = 0; f < 16; f++) sA[lane * 65 + f0 + f] = tanhf(acc[f]);
  __syncthreads();
  {  // coalesced store
    int r = tid >> 2, p = tid & 3;
    int n = nb0 + r;
    if (n < N) {
      const float* sp = &sA[r * 65 + p * 16];
      float* gp = h + (size_t)n * 64 + p * 16;
      #pragma unroll
      for (int q = 0; q < 4; q++)
        *(float4*)(gp + q * 4) = make_float4(sp[q*4+0], sp[q*4+1], sp[q*4+2], sp[q*4+3]);
    }
  }
}

// ---- feat = hin @ Wg; el/er ----
__global__ __launch_bounds__(256) void k_feat(const float* __restrict__ hin,
                                              const float* __restrict__ wt,
                                              const float* __restrict__ al,
                                              const float* __restrict__ ar,
                                              float* __restrict__ feat,
                                              float* __restrict__ el,
                                              float* __restrict__ er, int N) {
  __shared__ float sA[64 * 65];
  __shared__ float sE[64 * 8];   // [node][el_w0..3, er_w0..3]
  int tid = threadIdx.x, lane = tid & 63, wv = tid >> 6;
  int nb0 = blockIdx.x * 64;
  int nl = N - 1;
  {
    int r = tid >> 2, p = tid & 3;
    const float* g = hin + (size_t)min(nb0 + r, nl) * 64 + p * 16;
    float4 v0 = *(const float4*)(g + 0), v1 = *(const float4*)(g + 4);
    float4 v2 = *(const float4*)(g + 8), v3 = *(const float4*)(g + 12);
    float* dp = &sA[r * 65 + p * 16];
    dp[0]=v0.x; dp[1]=v0.y; dp[2]=v0.z; dp[3]=v0.w;
    dp[4]=v1.x; dp[5]=v1.y; dp[6]=v1.z; dp[7]=v1.w;
    dp[8]=v2.x; dp[9]=v2.y; dp[10]=v2.z; dp[11]=v2.w;
    dp[12]=v3.x; dp[13]=v3.y; dp[14]=v3.z; dp[15]=v3.w;
  }
  __syncthreads();
  float a[64];
  #pragma unroll
  for (int k = 0; k < 64; k++) a[k] = sA[lane * 65 + k];
  int f0 = __builtin_amdgcn_readfirstlane(wv * 16);
  float acc[16];
  #pragma unroll
  for (int f = 0; f < 16; f++) acc[f] = 0.f;
  #pragma unroll
  for (int f = 0; f < 16; f++) {
    const float* wr = wt + (f0 + f) * 64;   // uniform -> s_load
    #pragma unroll
    for (int k = 0; k < 64; k++) acc[f] = fmaf(a[k], wr[k], acc[f]);
  }
  float rl = 0.f, rr = 0.f;
  #pragma unroll
  for (int f = 0; f < 16; f++) {
    rl = fmaf(acc[f], al[f0 + f], rl);
    rr = fmaf(acc[f], ar[f0 + f], rr);
  }
  __syncthreads();   // everyone's reg-hoist done; safe to overwrite sA
  #pragma unroll
  for (int f = 0; f < 16; f++) sA[lane * 65 + f0 + f] = acc[f];
  sE[lane * 8 + wv] = rl;
  sE[lane * 8 + 4 + wv] = rr;
  __syncthreads();
  {
    int r = tid >> 2, p = tid & 3;
    int n = nb0 + r;
    if (n < N) {
      const float* sp = &sA[r * 65 + p * 16];
      float* gp = feat + (size_t)n * 64 + p * 16;
      #pragma unroll
      for (int q = 0; q < 4; q++)
        *(float4*)(gp + q * 4) = make_float4(sp[q*4+0], sp[q*4+1], sp[q*4+2], sp[q*4+3]);
    }
  }
  if (tid < 64) {
    int n = nb0 + tid;
    if (n < N) {
      el[n] = (sE[tid*8+0] + sE[tid*8+1]) + (sE[tid*8+2] + sE[tid*8+3]);
      er[n] = (sE[tid*8+4] + sE[tid*8+5]) + (sE[tid*8+6] + sE[tid*8+7]);
    }
  }
}

// ---- edge softmax + aggregate: one wave per dst node, lane = feature ----
__global__ __launch_bounds__(256) void k_aggr(const float* __restrict__ feat,
                                              const float* __restrict__ el,
                                              const float* __restrict__ er,
                                              const int* __restrict__ row_ptr,
                                              const int* __restrict__ csr_src,
                                              unsigned char* __restrict__ mask,
                                              int write_mask, int use_mask,
                                              float* __restrict__ hout, int N) {
  __shared__ __align__(16) int   su[4][64];
  __shared__ __align__(16) float spl[4][64];
  int wv = (int)((blockIdx.x * blockDim.x + threadIdx.x) >> 6);
  int wave = threadIdx.x >> 6, lane = threadIdx.x & 63;
  if (wv >= N) return;
  int beg = row_ptr[wv], end = row_ptr[wv + 1];
  int deg = end - beg;
  float erv = er[wv];
  float acc0 = 0.f, acc1 = 0.f, acc2 = 0.f, acc3 = 0.f;
  if (deg <= 64) {
    int k = beg + lane;
    bool have = (lane < deg);
    int u = have ? csr_src[k] : 0;
    float sc = -INFINITY;
    if (have) {
      float e0 = el[u] + erv;
      sc = (e0 >= 0.f) ? e0 : 0.2f * e0;
      if (use_mask && mask[k] == 0) sc = -1e9f;
    }
    float m = sc;
    #pragma unroll
    for (int off = 32; off; off >>= 1) m = fmaxf(m, __shfl_xor(m, off, 64));
    float pl = have ? expf(sc - m) : 0.f;
    float s = pl;
    #pragma unroll
    for (int off = 32; off; off >>= 1) s += __shfl_xor(s, off, 64);
    pl *= 1.0f / fmaxf(s, 1e-9f);
    if (write_mask && have) mask[k] = (pl >= 0.01f) ? 1 : 0;
    su[wave][lane] = u;
    spl[wave][lane] = pl;
    int dq = (deg + 3) >> 2;
    #pragma unroll 2
    for (int q = 0; q < dq; q++) {
      int4   uu = *(const int4*)&su[wave][q * 4];
      float4 pp = *(const float4*)&spl[wave][q * 4];
      acc0 = fmaf(pp.x, feat[(size_t)uu.x * 64 + lane], acc0);
      acc1 = fmaf(pp.y, feat[(size_t)uu.y * 64 + lane], acc1);
      acc2 = fmaf(pp.z, feat[(size_t)uu.z * 64 + lane], acc2);
      acc3 = fmaf(pp.w, feat[(size_t)uu.w * 64 + lane], acc3);
    }
  } else {
    float m = -INFINITY, s = 0.f;
    for (int base = beg; base < end; base += 64) {
      int k = base + lane;
      float sc = -INFINITY;
      if (k < end) {
        int u = csr_src[k];
        float e0 = el[u] + erv;
        sc = (e0 >= 0.f) ? e0 : 0.2f * e0;
        if (use_mask && mask[k] == 0) sc = -1e9f;
      }
      float cm = sc;
      #pragma unroll
      for (int off = 32; off; off >>= 1) cm = fmaxf(cm, __shfl_xor(cm, off, 64));
      float nm = fmaxf(m, cm);
      float t = (k < end) ? expf(sc - nm) : 0.f;
      #pragma unroll
      for (int off = 32; off; off >>= 1) t += __shfl_xor(t, off, 64);
      s = s * expf(m - nm) + t;
      m = nm;
    }
    float inv = 1.0f / fmaxf(s, 1e-9f);
    for (int base = beg; base < end; base += 64) {
      int k = base + lane;
      int u = 0;
      float pl = 0.f;
      if (k < end) {
        u = csr_src[k];
        float e0 = el[u] + erv;
        float sc = (e0 >= 0.f) ? e0 : 0.2f * e0;
        if (use_mask && mask[k] == 0) sc = -1e9f;
        pl = expf(sc - m) * inv;
        if (write_mask) mask[k] = (pl >= 0.01f) ? 1 : 0;
      }
      su[wave][lane] = u;
      spl[wave][lane] = pl;
      int cnt = min(64, end - base);
      int dq = (cnt + 3) >> 2;
      for (int q = 0; q < dq; q++) {
        int4   uu = *(const int4*)&su[wave][q * 4];
        float4 pp = *(const float4*)&spl[wave][q * 4];
        acc0 = fmaf(pp.x, feat[(size_t)uu.x * 64 + lane], acc0);
        acc1 = fmaf(pp.y, feat[(size_t)uu.y * 64 + lane], acc1);
        acc2 = fmaf(pp.z, feat[(size_t)uu.z * 64 + lane], acc2);
        acc3 = fmaf(pp.w, feat[(size_t)uu.w * 64 + lane], acc3);
      }
    }
  }
  float acc = (acc0 + acc1) + (acc2 + acc3);
  hout[(size_t)wv * 64 + lane] = (acc > 0.f) ? acc : expm1f(acc);
}

// ---- fused MLP head: block=64 nodes, wave=16-feature chunk ----
__global__ __launch_bounds__(256) void k_mlp(const float* __restrict__ o0,
                                             const float* __restrict__ o1,
                                             const float* __restrict__ o2,
                                             const float* __restrict__ o3,
                                             const float* __restrict__ wt0,
                                             const float* __restrict__ b0,
                                             const float* __restrict__ wt1,
                                             const float* __restrict__ b1,
                                             const float* __restrict__ W2,
                                             const float* __restrict__ b2,
                                             float* __restrict__ out, int N) {
  __shared__ float sA[64 * 65];   // staged seg acts
  __shared__ float sB[64 * 65];   // layer-0 output exchange
  __shared__ float sR[64 * 5];    // layer-2 partials [node][wave]
  int tid = threadIdx.x, lane = tid & 63, wv = tid >> 6;
  int nb0 = blockIdx.x * 64;
  int nl = N - 1;
  int f0 = __builtin_amdgcn_readfirstlane(wv * 16);
  float acc[16];
  #pragma unroll
  for (int f = 0; f < 16; f++) acc[f] = b0[f0 + f];
  const float* segs[4] = {o0, o1, o2, o3};
  int r = tid >> 2, p = tid & 3;
  for (int sg = 0; sg < 4; sg++) {
    __syncthreads();   // prior iter's reg-hoists complete before restage
    {
      const float* g = segs[sg] + (size_t)min(nb0 + r, nl) * 64 + p * 16;
      float4 v0 = *(const float4*)(g + 0), v1 = *(const float4*)(g + 4);
      float4 v2 = *(const float4*)(g + 8), v3 = *(const float4*)(g + 12);
      float* dp = &sA[r * 65 + p * 16];
      dp[0]=v0.x; dp[1]=v0.y; dp[2]=v0.z; dp[3]=v0.w;
      dp[4]=v1.x; dp[5]=v1.y; dp[6]=v1.z; dp[7]=v1.w;
      dp[8]=v2.x; dp[9]=v2.y; dp[10]=v2.z; dp[11]=v2.w;
      dp[12]=v3.x; dp[13]=v3.y; dp[14]=v3.z; dp[15]=v3.w;
    }
    __syncthreads();
    float a[64];
    #pragma unroll
    for (int k = 0; k < 64; k++) a[k] = sA[lane * 65 + k];
    #pragma unroll
    for (int f = 0; f < 16; f++) {
      const float* wr = wt0 + (f0 + f) * 256 + sg * 64;   // uniform -> s_load
      #pragma unroll
      for (int k = 0; k < 64; k++) acc[f] = fmaf(a[k], wr[k], acc[f]);
    }
  }
  // layer-0 relu -> cross-wave exchange
  #pragma unroll
  for (int f = 0; f < 16; f++)
    sB[lane * 65 + f0 + f] = (acc[f] > 0.f) ? acc[f] : 0.f;
  __syncthreads();
  float a0[64];
  #pragma unroll
  for (int k = 0; k < 64; k++) a0[k] = sB[lane * 65 + k];
  float rp = 0.f;
  #pragma unroll
  for (int f = 0; f < 16; f++) {
    float a1 = b1[f0 + f];
    const float* wr = wt1 + (f0 + f) * 64;                // uniform -> s_load
    #pragma unroll
    for (int k = 0; k < 64; k++) a1 = fmaf(a0[k], wr[k], a1);
    float t = (a1 > 0.f) ? a1 : 0.f;
    rp = fmaf(t, W2[f0 + f], rp);
  }
  sR[lane * 5 + wv] = rp;
  __syncthreads();
  if (tid < 64) {
    int n = nb0 + tid;
    if (n < N) {
      float o = (sR[tid*5+0] + sR[tid*5+1]) + (sR[tid*5+2] + sR[tid*5+3]) + b2[0];
      out[n] = (o > 0.f) ? o : 0.f;
    }
  }
}

extern "C" void kernel_launch(void* const* d_in, const int* in_sizes, int n_in,
                              void* d_out, int out_size, void* d_ws, size_t ws_size,
                              hipStream_t stream) {
  const float* x       = (const float*)d_in[0];
  const int*   esrc    = (const int*)d_in[1];
  const int*   edst    = (const int*)d_in[2];
  const float* W_embed = (const float*)d_in[3];
  const float* W_gat   = (const float*)d_in[4];
  const float* a_l     = (const float*)d_in[5];
  const float* a_r     = (const float*)d_in[6];
  const float* W0      = (const float*)d_in[7];
  const float* b0      = (const float*)d_in[8];
  const float* W1      = (const float*)d_in[9];
  const float* b1      = (const float*)d_in[10];
  const float* W2      = (const float*)d_in[11];
  const float* b2      = (const float*)d_in[12];
  float* out = (float*)d_out;
  const int N = in_sizes[0] / 128;
  const int E = in_sizes[1];

  char* p = (char*)d_ws;
  auto alloc = [&](size_t bytes) -> char* {
    char* r = p;
    p += (bytes + 255) & ~(size_t)255;
    return r;
  };
  float* out0 = (float*)alloc((size_t)N * 64 * 4);
  float* out1 = (float*)alloc((size_t)N * 64 * 4);
  float* out2 = (float*)alloc((size_t)N * 64 * 4);
  float* out3 = (float*)alloc((size_t)N * 64 * 4);
  float* h    = out3;  // alias: h dead before out3 written
  float* feat = (float*)alloc((size_t)N * 64 * 4);
  float* el   = (float*)alloc((size_t)N * 4);
  float* er   = (float*)alloc((size_t)N * 4);
  int* counts  = (int*)alloc((size_t)N * 4);
  int* row_ptr = (int*)alloc((size_t)(N + 1) * 4);
  int* cursor  = (int*)alloc((size_t)N * 4);
  int* csr_src = (int*)alloc((size_t)E * 4);
  unsigned char* mask = (unsigned char*)alloc((size_t)E);
  int nb = (N + 1023) / 1024;
  int* bsum = (int*)alloc((size_t)nb * 4);
  int* bofs = (int*)alloc((size_t)nb * 4);
  float* wt = (float*)alloc((size_t)WT_TOT * 4);

  // --- prep: zero counts + transpose all weight matrices ---
  int prep_n = (N > WT_TOT) ? N : WT_TOT;
  k_prep<<<(prep_n + 255) / 256, 256, 0, stream>>>(W_embed, W_gat, W0, W1,
                                                   wt, counts, N);

  // --- CSR build (dst-sorted) ---
  k_hist<<<(E + 255) / 256, 256, 0, stream>>>(edst, counts, E);
  k_bsum<<<nb, 1024, 0, stream>>>(counts, bsum, N);
  k_bscan<<<1, 64, 0, stream>>>(bsum, bofs, row_ptr, nb, N);
  k_scan3<<<nb, 1024, 0, stream>>>(counts, bofs, row_ptr, cursor, N);
  k_scatter<<<(E + 255) / 256, 256, 0, stream>>>(esrc, edst, cursor, csr_src, E);

  // --- dense grid: 64 nodes per 256-thread block ---
  int dgb = (N + 63) / 64;
  k_embed<<<dgb, 256, 0, stream>>>(x, wt + WT_EMB, h, N);

  // --- 4 conv layers ---
  const float* hin = h;
  float* outs[4] = {out0, out1, out2, out3};
  for (int l = 0; l < 4; l++) {
    k_feat<<<dgb, 256, 0, stream>>>(hin, wt + WT_GAT + (size_t)l * 4096,
                                    a_l + (size_t)l * 64, a_r + (size_t)l * 64,
                                    feat, el, er, N);
    k_aggr<<<(N + 3) / 4, 256, 0, stream>>>(feat, el, er, row_ptr, csr_src, mask,
                                            (l == 0) ? 1 : 0, (l > 0) ? 1 : 0,
                                            outs[l], N);
    hin = outs[l];
  }

  // --- MLP head ---
  k_mlp<<<dgb, 256, 0, stream>>>(out0, out1, out2, out3, wt + WT_W0, b0,
                                 wt + WT_W1, b1, W2, b2, out, N);
}

// Round 7
// 521.266 us; speedup vs baseline: 2.1102x; 1.0107x over previous
//
#include <hip/hip_runtime.h>
#include <math.h>

// ---------------------------------------------------------------------------
// SNAT3: 4-layer GAT GNN. N=50000, E=800000, HID=64, fp32.
// R7: R6 structure (block=256thr=64 nodes, lane=node, wave owns 16 features,
// weights via wave-uniform s_load from transposed wt, acts hoisted from LDS
// to VGPRs) with two fixes:
//  - __launch_bounds__(256,3): grid is ~3 blocks/CU anyway; cap VGPR at ~170
//    so the a[64] activation hoist actually stays in registers (R6 compiled
//    to 52 VGPRs -> streamed LDS reads in the FMA loop -> VALUBusy 35%).
//  - k_embed fused with layer-0 k_feat (feat0 is row-wise in h) -> h never
//    materialized (saves a dispatch + 25 MB of HBM/L3 round-trip).
// ---------------------------------------------------------------------------

#define WT_EMB 0
#define WT_GAT 8192
#define WT_W0  24576
#define WT_W1  40960
#define WT_TOT 45056

__global__ void k_prep(const float* __restrict__ We, const float* __restrict__ Wg,
                       const float* __restrict__ W0, const float* __restrict__ W1,
                       float* __restrict__ wt, int* __restrict__ counts, int N) {
  int i = blockIdx.x * 256 + threadIdx.x;
  if (i < N) counts[i] = 0;
  if (i < 8192) {                       // W_embed [128][64] -> [64f][128k]
    int k = i >> 6, f = i & 63;
    wt[WT_EMB + f * 128 + k] = We[i];
  } else if (i < 24576) {               // W_gat [4][64][64] -> [4][64f][64k]
    int j = i - 8192, l = j >> 12, r = j & 4095;
    int k = r >> 6, f = r & 63;
    wt[WT_GAT + l * 4096 + f * 64 + k] = Wg[j];
  } else if (i < 40960) {               // W0 [256][64] -> [64f][256k]
    int j = i - 24576, k = j >> 6, f = j & 63;
    wt[WT_W0 + f * 256 + k] = W0[j];
  } else if (i < WT_TOT) {              // W1 [64][64] -> [64f][64k]
    int j = i - 40960, k = j >> 6, f = j & 63;
    wt[WT_W1 + f * 64 + k] = W1[j];
  }
}

__global__ void k_hist(const int* __restrict__ dst, int* __restrict__ counts, int E) {
  int e = blockIdx.x * blockDim.x + threadIdx.x;
  if (e < E) atomicAdd(&counts[dst[e]], 1);
}

__global__ __launch_bounds__(1024) void k_bsum(const int* __restrict__ counts,
                                               int* __restrict__ bsum, int n) {
  __shared__ int wsum[16];
  int tid = threadIdx.x, lane = tid & 63, wid = tid >> 6;
  int i = blockIdx.x * 1024 + tid;
  int v = (i < n) ? counts[i] : 0;
  #pragma unroll
  for (int off = 32; off; off >>= 1) v += __shfl_xor(v, off, 64);
  if (lane == 0) wsum[wid] = v;
  __syncthreads();
  if (wid == 0) {
    int w = (lane < 16) ? wsum[lane] : 0;
    #pragma unroll
    for (int off = 8; off; off >>= 1) w += __shfl_xor(w, off, 64);
    if (lane == 0) bsum[blockIdx.x] = w;
  }
}

__global__ __launch_bounds__(64) void k_bscan(const int* __restrict__ bsum,
                                              int* __restrict__ bofs,
                                              int* __restrict__ row_ptr,
                                              int nb, int n) {
  int lane = threadIdx.x;
  int carry = 0;
  for (int base = 0; base < nb; base += 64) {
    int idx = base + lane;
    int orig = (idx < nb) ? bsum[idx] : 0;
    int inc = orig;
    #pragma unroll
    for (int off = 1; off < 64; off <<= 1) {
      int t = __shfl_up(inc, off, 64);
      if (lane >= off) inc += t;
    }
    if (idx < nb) bofs[idx] = carry + inc - orig;
    carry += __shfl(inc, 63, 64);
  }
  if (lane == 0) row_ptr[n] = carry;
}

__global__ __launch_bounds__(1024) void k_scan3(const int* __restrict__ counts,
                                                const int* __restrict__ bofs,
                                                int* __restrict__ row_ptr,
                                                int* __restrict__ cursor, int n) {
  __shared__ int wsum[16];
  int tid = threadIdx.x, lane = tid & 63, wid = tid >> 6;
  int i = blockIdx.x * 1024 + tid;
  int v = (i < n) ? counts[i] : 0;
  int inc = v;
  #pragma unroll
  for (int off = 1; off < 64; off <<= 1) {
    int t = __shfl_up(inc, off, 64);
    if (lane >= off) inc += t;
  }
  if (lane == 63) wsum[wid] = inc;
  __syncthreads();
  if (wid == 0 && lane < 16) {
    int orig = wsum[lane];
    int w = orig;
    #pragma unroll
    for (int off = 1; off < 16; off <<= 1) {
      int t = __shfl_up(w, off, 64);
      if (lane >= off) w += t;
    }
    wsum[lane] = w - orig;
  }
  __syncthreads();
  int excl = bofs[blockIdx.x] + wsum[wid] + inc - v;
  if (i < n) { row_ptr[i] = excl; cursor[i] = excl; }
}

__global__ void k_scatter(const int* __restrict__ src, const int* __restrict__ dst,
                          int* __restrict__ cursor, int* __restrict__ csr_src, int E) {
  int e = blockIdx.x * blockDim.x + threadIdx.x;
  if (e < E) {
    int pos = atomicAdd(&cursor[dst[e]], 1);
    csr_src[pos] = src[e];
  }
}

// ---- fused: h = tanh(x@We); feat = h@Wg0; el/er.  h never hits global ----
__global__ __launch_bounds__(256, 3) void k_embed_feat(
    const float* __restrict__ x, const float* __restrict__ wte,
    const float* __restrict__ wtg, const float* __restrict__ al,
    const float* __restrict__ ar, float* __restrict__ feat,
    float* __restrict__ el, float* __restrict__ er, int N) {
  __shared__ float sA[64 * 129];  // x staging (33KB); reused as 64x65 exchange
  __shared__ float sE[64 * 8];
  int tid = threadIdx.x, lane = tid & 63, wv = tid >> 6;
  int nb0 = blockIdx.x * 64, nl = N - 1;
  int r = tid >> 2, p = tid & 3;
  {
    const float* gp = x + (size_t)min(nb0 + r, nl) * 128;
    #pragma unroll
    for (int half = 0; half < 2; half++) {
      const float* g = gp + half * 64 + p * 16;
      float4 v0 = *(const float4*)(g + 0), v1 = *(const float4*)(g + 4);
      float4 v2 = *(const float4*)(g + 8), v3 = *(const float4*)(g + 12);
      float* dp = &sA[r * 129 + half * 64 + p * 16];
      dp[0]=v0.x; dp[1]=v0.y; dp[2]=v0.z; dp[3]=v0.w;
      dp[4]=v1.x; dp[5]=v1.y; dp[6]=v1.z; dp[7]=v1.w;
      dp[8]=v2.x; dp[9]=v2.y; dp[10]=v2.z; dp[11]=v2.w;
      dp[12]=v3.x; dp[13]=v3.y; dp[14]=v3.z; dp[15]=v3.w;
    }
  }
  __syncthreads();
  int f0 = __builtin_amdgcn_readfirstlane(wv * 16);
  float acc[16];
  #pragma unroll
  for (int f = 0; f < 16; f++) acc[f] = 0.f;
  for (int kc = 0; kc < 2; kc++) {
    float a[64];
    #pragma unroll
    for (int k = 0; k < 64; k++) a[k] = sA[lane * 129 + kc * 64 + k];
    #pragma unroll
    for (int f = 0; f < 16; f++) {
      const float* wr = wte + (f0 + f) * 128 + kc * 64;  // uniform -> s_load
      #pragma unroll
      for (int k = 0; k < 64; k++) acc[f] = fmaf(a[k], wr[k], acc[f]);
    }
  }
  __syncthreads();  // x reads done; reuse sA as h exchange (64x65)
  #pragma unroll
  for (int f = 0; f < 16; f++) sA[lane * 65 + f0 + f] = tanhf(acc[f]);
  __syncthreads();
  float a0[64];
  #pragma unroll
  for (int k = 0; k < 64; k++) a0[k] = sA[lane * 65 + k];
  float acc2[16];
  #pragma unroll
  for (int f = 0; f < 16; f++) acc2[f] = 0.f;
  #pragma unroll
  for (int f = 0; f < 16; f++) {
    const float* wr = wtg + (f0 + f) * 64;               // uniform -> s_load
    #pragma unroll
    for (int k = 0; k < 64; k++) acc2[f] = fmaf(a0[k], wr[k], acc2[f]);
  }
  float rl = 0.f, rr = 0.f;
  #pragma unroll
  for (int f = 0; f < 16; f++) {
    rl = fmaf(acc2[f], al[f0 + f], rl);
    rr = fmaf(acc2[f], ar[f0 + f], rr);
  }
  sE[lane * 8 + wv] = rl;
  sE[lane * 8 + 4 + wv] = rr;
  __syncthreads();  // all a0 rehoists done; safe to overwrite sA
  #pragma unroll
  for (int f = 0; f < 16; f++) sA[lane * 65 + f0 + f] = acc2[f];
  __syncthreads();
  {
    int n = nb0 + r;
    if (n < N) {
      const float* sp = &sA[r * 65 + p * 16];
      float* gp = feat + (size_t)n * 64 + p * 16;
      #pragma unroll
      for (int q = 0; q < 4; q++)
        *(float4*)(gp + q * 4) = make_float4(sp[q*4+0], sp[q*4+1], sp[q*4+2], sp[q*4+3]);
    }
  }
  if (tid < 64) {
    int n = nb0 + tid;
    if (n < N) {
      el[n] = (sE[tid*8+0] + sE[tid*8+1]) + (sE[tid*8+2] + sE[tid*8+3]);
      er[n] = (sE[tid*8+4] + sE[tid*8+5]) + (sE[tid*8+6] + sE[tid*8+7]);
    }
  }
}

// ---- feat = hin @ Wg; el/er (layers 1..3) ----
__global__ __launch_bounds__(256, 3) void k_feat(const float* __restrict__ hin,
                                                 const float* __restrict__ wt,
                                                 const float* __restrict__ al,
                                                 const float* __restrict__ ar,
                                                 float* __restrict__ feat,
                                                 float* __restrict__ el,
                                                 float* __restrict__ er, int N) {
  __shared__ float sA[64 * 65];
  __shared__ float sE[64 * 8];
  int tid = threadIdx.x, lane = tid & 63, wv = tid >> 6;
  int nb0 = blockIdx.x * 64;
  int nl = N - 1;
  int r = tid >> 2, p = tid & 3;
  {
    const float* g = hin + (size_t)min(nb0 + r, nl) * 64 + p * 16;
    float4 v0 = *(const float4*)(g + 0), v1 = *(const float4*)(g + 4);
    float4 v2 = *(const float4*)(g + 8), v3 = *(const float4*)(g + 12);
    float* dp = &sA[r * 65 + p * 16];
    dp[0]=v0.x; dp[1]=v0.y; dp[2]=v0.z; dp[3]=v0.w;
    dp[4]=v1.x; dp[5]=v1.y; dp[6]=v1.z; dp[7]=v1.w;
    dp[8]=v2.x; dp[9]=v2.y; dp[10]=v2.z; dp[11]=v2.w;
    dp[12]=v3.x; dp[13]=v3.y; dp[14]=v3.z; dp[15]=v3.w;
  }
  __syncthreads();
  float a[64];
  #pragma unroll
  for (int k = 0; k < 64; k++) a[k] = sA[lane * 65 + k];
  int f0 = __builtin_amdgcn_readfirstlane(wv * 16);
  float acc[16];
  #pragma unroll
  for (int f = 0; f < 16; f++) acc[f] = 0.f;
  #pragma unroll
  for (int f = 0; f < 16; f++) {
    const float* wr = wt + (f0 + f) * 64;   // uniform -> s_load
    #pragma unroll
    for (int k = 0; k < 64; k++) acc[f] = fmaf(a[k], wr[k], acc[f]);
  }
  float rl = 0.f, rr = 0.f;
  #pragma unroll
  for (int f = 0; f < 16; f++) {
    rl = fmaf(acc[f], al[f0 + f], rl);
    rr = fmaf(acc[f], ar[f0 + f], rr);
  }
  __syncthreads();
  #pragma unroll
  for (int f = 0; f < 16; f++) sA[lane * 65 + f0 + f] = acc[f];
  sE[lane * 8 + wv] = rl;
  sE[lane * 8 + 4 + wv] = rr;
  __syncthreads();
  {
    int n = nb0 + r;
    if (n < N) {
      const float* sp = &sA[r * 65 + p * 16];
      float* gp = feat + (size_t)n * 64 + p * 16;
      #pragma unroll
      for (int q = 0; q < 4; q++)
        *(float4*)(gp + q * 4) = make_float4(sp[q*4+0], sp[q*4+1], sp[q*4+2], sp[q*4+3]);
    }
  }
  if (tid < 64) {
    int n = nb0 + tid;
    if (n < N) {
      el[n] = (sE[tid*8+0] + sE[tid*8+1]) + (sE[tid*8+2] + sE[tid*8+3]);
      er[n] = (sE[tid*8+4] + sE[tid*8+5]) + (sE[tid*8+6] + sE[tid*8+7]);
    }
  }
}

// ---- edge softmax + aggregate: one wave per dst node, lane = feature ----
__global__ __launch_bounds__(256) void k_aggr(const float* __restrict__ feat,
                                              const float* __restrict__ el,
                                              const float* __restrict__ er,
                                              const int* __restrict__ row_ptr,
                                              const int* __restrict__ csr_src,
                                              unsigned char* __restrict__ mask,
                                              int write_mask, int use_mask,
                                              float* __restrict__ hout, int N) {
  __shared__ __align__(16) int   su[4][64];
  __shared__ __align__(16) float spl[4][64];
  int wv = (int)((blockIdx.x * blockDim.x + threadIdx.x) >> 6);
  int wave = threadIdx.x >> 6, lane = threadIdx.x & 63;
  if (wv >= N) return;
  int beg = row_ptr[wv], end = row_ptr[wv + 1];
  int deg = end - beg;
  float erv = er[wv];
  float acc0 = 0.f, acc1 = 0.f, acc2 = 0.f, acc3 = 0.f;
  if (deg <= 64) {
    int k = beg + lane;
    bool have = (lane < deg);
    int u = have ? csr_src[k] : 0;
    float sc = -INFINITY;
    if (have) {
      float e0 = el[u] + erv;
      sc = (e0 >= 0.f) ? e0 : 0.2f * e0;
      if (use_mask && mask[k] == 0) sc = -1e9f;
    }
    float m = sc;
    #pragma unroll
    for (int off = 32; off; off >>= 1) m = fmaxf(m, __shfl_xor(m, off, 64));
    float pl = have ? expf(sc - m) : 0.f;
    float s = pl;
    #pragma unroll
    for (int off = 32; off; off >>= 1) s += __shfl_xor(s, off, 64);
    pl *= 1.0f / fmaxf(s, 1e-9f);
    if (write_mask && have) mask[k] = (pl >= 0.01f) ? 1 : 0;
    su[wave][lane] = u;
    spl[wave][lane] = pl;
    int dq = (deg + 3) >> 2;
    #pragma unroll 2
    for (int q = 0; q < dq; q++) {
      int4   uu = *(const int4*)&su[wave][q * 4];
      float4 pp = *(const float4*)&spl[wave][q * 4];
      acc0 = fmaf(pp.x, feat[(size_t)uu.x * 64 + lane], acc0);
      acc1 = fmaf(pp.y, feat[(size_t)uu.y * 64 + lane], acc1);
      acc2 = fmaf(pp.z, feat[(size_t)uu.z * 64 + lane], acc2);
      acc3 = fmaf(pp.w, feat[(size_t)uu.w * 64 + lane], acc3);
    }
  } else {
    float m = -INFINITY, s = 0.f;
    for (int base = beg; base < end; base += 64) {
      int k = base + lane;
      float sc = -INFINITY;
      if (k < end) {
        int u = csr_src[k];
        float e0 = el[u] + erv;
        sc = (e0 >= 0.f) ? e0 : 0.2f * e0;
        if (use_mask && mask[k] == 0) sc = -1e9f;
      }
      float cm = sc;
      #pragma unroll
      for (int off = 32; off; off >>= 1) cm = fmaxf(cm, __shfl_xor(cm, off, 64));
      float nm = fmaxf(m, cm);
      float t = (k < end) ? expf(sc - nm) : 0.f;
      #pragma unroll
      for (int off = 32; off; off >>= 1) t += __shfl_xor(t, off, 64);
      s = s * expf(m - nm) + t;
      m = nm;
    }
    float inv = 1.0f / fmaxf(s, 1e-9f);
    for (int base = beg; base < end; base += 64) {
      int k = base + lane;
      int u = 0;
      float pl = 0.f;
      if (k < end) {
        u = csr_src[k];
        float e0 = el[u] + erv;
        float sc = (e0 >= 0.f) ? e0 : 0.2f * e0;
        if (use_mask && mask[k] == 0) sc = -1e9f;
        pl = expf(sc - m) * inv;
        if (write_mask) mask[k] = (pl >= 0.01f) ? 1 : 0;
      }
      su[wave][lane] = u;
      spl[wave][lane] = pl;
      int cnt = min(64, end - base);
      int dq = (cnt + 3) >> 2;
      for (int q = 0; q < dq; q++) {
        int4   uu = *(const int4*)&su[wave][q * 4];
        float4 pp = *(const float4*)&spl[wave][q * 4];
        acc0 = fmaf(pp.x, feat[(size_t)uu.x * 64 + lane], acc0);
        acc1 = fmaf(pp.y, feat[(size_t)uu.y * 64 + lane], acc1);
        acc2 = fmaf(pp.z, feat[(size_t)uu.z * 64 + lane], acc2);
        acc3 = fmaf(pp.w, feat[(size_t)uu.w * 64 + lane], acc3);
      }
    }
  }
  float acc = (acc0 + acc1) + (acc2 + acc3);
  hout[(size_t)wv * 64 + lane] = (acc > 0.f) ? acc : expm1f(acc);
}

// ---- fused MLP head: block=64 nodes, wave=16-feature chunk ----
__global__ __launch_bounds__(256, 3) void k_mlp(const float* __restrict__ o0,
                                                const float* __restrict__ o1,
                                                const float* __restrict__ o2,
                                                const float* __restrict__ o3,
                                                const float* __restrict__ wt0,
                                                const float* __restrict__ b0,
                                                const float* __restrict__ wt1,
                                                const float* __restrict__ b1,
                                                const float* __restrict__ W2,
                                                const float* __restrict__ b2,
                                                float* __restrict__ out, int N) {
  __shared__ float sA[64 * 65];   // staged seg acts
  __shared__ float sB[64 * 65];   // layer-0 output exchange
  __shared__ float sR[64 * 5];    // layer-2 partials [node][wave]
  int tid = threadIdx.x, lane = tid & 63, wv = tid >> 6;
  int nb0 = blockIdx.x * 64;
  int nl = N - 1;
  int f0 = __builtin_amdgcn_readfirstlane(wv * 16);
  float acc[16];
  #pragma unroll
  for (int f = 0; f < 16; f++) acc[f] = b0[f0 + f];
  const float* segs[4] = {o0, o1, o2, o3};
  int r = tid >> 2, p = tid & 3;
  for (int sg = 0; sg < 4; sg++) {
    __syncthreads();   // prior iter's reg-hoists complete before restage
    {
      const float* g = segs[sg] + (size_t)min(nb0 + r, nl) * 64 + p * 16;
      float4 v0 = *(const float4*)(g + 0), v1 = *(const float4*)(g + 4);
      float4 v2 = *(const float4*)(g + 8), v3 = *(const float4*)(g + 12);
      float* dp = &sA[r * 65 + p * 16];
      dp[0]=v0.x; dp[1]=v0.y; dp[2]=v0.z; dp[3]=v0.w;
      dp[4]=v1.x; dp[5]=v1.y; dp[6]=v1.z; dp[7]=v1.w;
      dp[8]=v2.x; dp[9]=v2.y; dp[10]=v2.z; dp[11]=v2.w;
      dp[12]=v3.x; dp[13]=v3.y; dp[14]=v3.z; dp[15]=v3.w;
    }
    __syncthreads();
    float a[64];
    #pragma unroll
    for (int k = 0; k < 64; k++) a[k] = sA[lane * 65 + k];
    #pragma unroll
    for (int f = 0; f < 16; f++) {
      const float* wr = wt0 + (f0 + f) * 256 + sg * 64;   // uniform -> s_load
      #pragma unroll
      for (int k = 0; k < 64; k++) acc[f] = fmaf(a[k], wr[k], acc[f]);
    }
  }
  // layer-0 relu -> cross-wave exchange
  #pragma unroll
  for (int f = 0; f < 16; f++)
    sB[lane * 65 + f0 + f] = (acc[f] > 0.f) ? acc[f] : 0.f;
  __syncthreads();
  float a0[64];
  #pragma unroll
  for (int k = 0; k < 64; k++) a0[k] = sB[lane * 65 + k];
  float rp = 0.f;
  #pragma unroll
  for (int f = 0; f < 16; f++) {
    float a1 = b1[f0 + f];
    const float* wr = wt1 + (f0 + f) * 64;                // uniform -> s_load
    #pragma unroll
    for (int k = 0; k < 64; k++) a1 = fmaf(a0[k], wr[k], a1);
    float t = (a1 > 0.f) ? a1 : 0.f;
    rp = fmaf(t, W2[f0 + f], rp);
  }
  sR[lane * 5 + wv] = rp;
  __syncthreads();
  if (tid < 64) {
    int n = nb0 + tid;
    if (n < N) {
      float o = (sR[tid*5+0] + sR[tid*5+1]) + (sR[tid*5+2] + sR[tid*5+3]) + b2[0];
      out[n] = (o > 0.f) ? o : 0.f;
    }
  }
}

extern "C" void kernel_launch(void* const* d_in, const int* in_sizes, int n_in,
                              void* d_out, int out_size, void* d_ws, size_t ws_size,
                              hipStream_t stream) {
  const float* x       = (const float*)d_in[0];
  const int*   esrc    = (const int*)d_in[1];
  const int*   edst    = (const int*)d_in[2];
  const float* W_embed = (const float*)d_in[3];
  const float* W_gat   = (const float*)d_in[4];
  const float* a_l     = (const float*)d_in[5];
  const float* a_r     = (const float*)d_in[6];
  const float* W0      = (const float*)d_in[7];
  const float* b0      = (const float*)d_in[8];
  const float* W1      = (const float*)d_in[9];
  const float* b1      = (const float*)d_in[10];
  const float* W2      = (const float*)d_in[11];
  const float* b2      = (const float*)d_in[12];
  float* out = (float*)d_out;
  const int N = in_sizes[0] / 128;
  const int E = in_sizes[1];

  char* p = (char*)d_ws;
  auto alloc = [&](size_t bytes) -> char* {
    char* r = p;
    p += (bytes + 255) & ~(size_t)255;
    return r;
  };
  float* out0 = (float*)alloc((size_t)N * 64 * 4);
  float* out1 = (float*)alloc((size_t)N * 64 * 4);
  float* out2 = (float*)alloc((size_t)N * 64 * 4);
  float* out3 = (float*)alloc((size_t)N * 64 * 4);
  float* feat = (float*)alloc((size_t)N * 64 * 4);
  float* el   = (float*)alloc((size_t)N * 4);
  float* er   = (float*)alloc((size_t)N * 4);
  int* counts  = (int*)alloc((size_t)N * 4);
  int* row_ptr = (int*)alloc((size_t)(N + 1) * 4);
  int* cursor  = (int*)alloc((size_t)N * 4);
  int* csr_src = (int*)alloc((size_t)E * 4);
  unsigned char* mask = (unsigned char*)alloc((size_t)E);
  int nb = (N + 1023) / 1024;
  int* bsum = (int*)alloc((size_t)nb * 4);
  int* bofs = (int*)alloc((size_t)nb * 4);
  float* wt = (float*)alloc((size_t)WT_TOT * 4);

  // --- prep: zero counts + transpose all weight matrices ---
  int prep_n = (N > WT_TOT) ? N : WT_TOT;
  k_prep<<<(prep_n + 255) / 256, 256, 0, stream>>>(W_embed, W_gat, W0, W1,
                                                   wt, counts, N);

  // --- CSR build (dst-sorted) ---
  k_hist<<<(E + 255) / 256, 256, 0, stream>>>(edst, counts, E);
  k_bsum<<<nb, 1024, 0, stream>>>(counts, bsum, N);
  k_bscan<<<1, 64, 0, stream>>>(bsum, bofs, row_ptr, nb, N);
  k_scan3<<<nb, 1024, 0, stream>>>(counts, bofs, row_ptr, cursor, N);
  k_scatter<<<(E + 255) / 256, 256, 0, stream>>>(esrc, edst, cursor, csr_src, E);

  // --- dense grid: 64 nodes per 256-thread block ---
  int dgb = (N + 63) / 64;

  // --- layer 0: fused embed + feat ---
  k_embed_feat<<<dgb, 256, 0, stream>>>(x, wt + WT_EMB, wt + WT_GAT,
                                        a_l, a_r, feat, el, er, N);
  float* outs[4] = {out0, out1, out2, out3};
  k_aggr<<<(N + 3) / 4, 256, 0, stream>>>(feat, el, er, row_ptr, csr_src, mask,
                                          1, 0, out0, N);

  // --- layers 1..3 ---
  for (int l = 1; l < 4; l++) {
    k_feat<<<dgb, 256, 0, stream>>>(outs[l - 1], wt + WT_GAT + (size_t)l * 4096,
                                    a_l + (size_t)l * 64, a_r + (size_t)l * 64,
                                    feat, el, er, N);
    k_aggr<<<(N + 3) / 4, 256, 0, stream>>>(feat, el, er, row_ptr, csr_src, mask,
                                            0, 1, outs[l], N);
  }

  // --- MLP head ---
  k_mlp<<<dgb, 256, 0, stream>>>(out0, out1, out2, out3, wt + WT_W0, b0,
                                 wt + WT_W1, b1, W2, b2, out, N);
}